// Round 1
// baseline (7044.633 us; speedup 1.0000x reference)
//
#include <hip/hip_runtime.h>
#include <hip/hip_bf16.h>
#include <stdint.h>

#define BB   64
#define TT   2048
#define II   256
#define HH   256
#define G4   1024   // 4*H
#define NC   10

typedef _Float16 half2v __attribute__((ext_vector_type(2)));
typedef _Float16 half8v __attribute__((ext_vector_type(8)));
typedef float    float4v __attribute__((ext_vector_type(4)));

__device__ __forceinline__ float fdot2(uint32_t w, uint32_t h, float acc) {
  return __builtin_amdgcn_fdot2(__builtin_bit_cast(half2v, w),
                                __builtin_bit_cast(half2v, h), acc, false);
}
__device__ __forceinline__ float sigmf(float v) { return 1.f / (1.f + __expf(-v)); }
__device__ __forceinline__ float tanhf2(float v) { float e = __expf(2.f * v); return 1.f - 2.f / (e + 1.f); }

// ---------------------------------------------------------------------------
// K0a: WcT[g][i] = sum_j key[i][j] * W_ih[g][j]  (f16), biasc[g] = b_ih+b_hh
// ---------------------------------------------------------------------------
__global__ __launch_bounds__(1024) void prep_wc(
    const float* __restrict__ key, const float* __restrict__ Wih,
    const float* __restrict__ bih, const float* __restrict__ bhh,
    _Float16* __restrict__ WcT, float* __restrict__ biasc) {
  __shared__ float krow[II];
  const int i = blockIdx.x;
  const int g = threadIdx.x;
  if (g < II) krow[g] = key[(size_t)i * II + g];
  __syncthreads();
  const float4* w4 = (const float4*)(Wih + (size_t)g * II);
  float acc = 0.f;
#pragma unroll 8
  for (int j = 0; j < II / 4; ++j) {
    float4 w = w4[j];
    acc += w.x * krow[4 * j] + w.y * krow[4 * j + 1] + w.z * krow[4 * j + 2] + w.w * krow[4 * j + 3];
  }
  WcT[(size_t)g * II + i] = (_Float16)acc;
  if (i == 0) biasc[g] = bih[g] + bhh[g];
}

// ---------------------------------------------------------------------------
// K0c: pack W_hh rows into f16-pair dwords.
//   wreg: [80][1024] dwords  (k-pairs 0..79, column = gate row g)  -> register resident
//   wst : [12][1024] uint4   (k-pairs 80..127, 4 dwords per chunk) -> streamed per step
// ---------------------------------------------------------------------------
__global__ __launch_bounds__(256) void prep_whh(
    const float* __restrict__ Whh, uint32_t* __restrict__ wreg, uint32_t* __restrict__ wst) {
  const int id = blockIdx.x * 256 + threadIdx.x;   // 131072
  const int g  = id & (G4 - 1);
  const int kp = id >> 10;                          // 0..127
  float a = Whh[(size_t)g * HH + 2 * kp];
  float b = Whh[(size_t)g * HH + 2 * kp + 1];
  half2v h = {(_Float16)a, (_Float16)b};
  uint32_t packed = __builtin_bit_cast(uint32_t, h);
  if (kp < 80) {
    wreg[kp * G4 + g] = packed;
  } else {
    int c = (kp - 80) >> 2, j = (kp - 80) & 3;
    wst[(c * G4 + g) * 4 + j] = packed;
  }
}

// ---------------------------------------------------------------------------
// K1: x_proj[m][g] = sum_i x[m][i]*WcT[g][i] + biasc[g]   (f16 out, fp32 acc)
//   128x128 tile, 256 threads (4 waves, each 64x64 = 4x4 MFMA 16x16x32 f16)
// ---------------------------------------------------------------------------
__global__ __launch_bounds__(256) void gemm_xproj(
    const float* __restrict__ x, const _Float16* __restrict__ WcT,
    const float* __restrict__ biasc, _Float16* __restrict__ xproj) {
  __shared__ __align__(16) _Float16 Asm[128][40];   // pad: 40 f16 = 80 B rows
  __shared__ __align__(16) _Float16 Bsm[128][40];
  const int t = threadIdx.x;
  const int n0 = blockIdx.x * 128;
  const int m0 = blockIdx.y * 128;
  const int r = t >> 1;
  const int hoff = (t & 1) * 16;
  const int lane = t & 63, wave = t >> 6;
  const int quad = lane >> 4, l15 = lane & 15;
  const int mh = (wave & 1) * 64, nh = (wave >> 1) * 64;
  float4v zero = {0.f, 0.f, 0.f, 0.f};
  float4v acc[4][4];
#pragma unroll
  for (int a = 0; a < 4; ++a)
#pragma unroll
    for (int b = 0; b < 4; ++b) acc[a][b] = zero;

  for (int kt = 0; kt < 8; ++kt) {
    const int k0 = kt * 32;
    // stage A (fp32 -> f16)
    const float4* xa = (const float4*)(x + (size_t)(m0 + r) * II + k0 + hoff);
    float4 f0 = xa[0], f1 = xa[1], f2 = xa[2], f3 = xa[3];
    half8v lo = {(_Float16)f0.x, (_Float16)f0.y, (_Float16)f0.z, (_Float16)f0.w,
                 (_Float16)f1.x, (_Float16)f1.y, (_Float16)f1.z, (_Float16)f1.w};
    half8v hi = {(_Float16)f2.x, (_Float16)f2.y, (_Float16)f2.z, (_Float16)f2.w,
                 (_Float16)f3.x, (_Float16)f3.y, (_Float16)f3.z, (_Float16)f3.w};
    // stage B (already f16, already n-major)
    const half8v* bsrc = (const half8v*)(WcT + (size_t)(n0 + r) * II + k0 + hoff);
    half8v b0 = bsrc[0], b1 = bsrc[1];
    *(half8v*)&Asm[r][hoff]     = lo;
    *(half8v*)&Asm[r][hoff + 8] = hi;
    *(half8v*)&Bsm[r][hoff]     = b0;
    *(half8v*)&Bsm[r][hoff + 8] = b1;
    __syncthreads();
    half8v af[4], bf[4];
#pragma unroll
    for (int mt = 0; mt < 4; ++mt) af[mt] = *(const half8v*)&Asm[mh + mt * 16 + l15][quad * 8];
#pragma unroll
    for (int nt = 0; nt < 4; ++nt) bf[nt] = *(const half8v*)&Bsm[nh + nt * 16 + l15][quad * 8];
#pragma unroll
    for (int mt = 0; mt < 4; ++mt)
#pragma unroll
      for (int nt = 0; nt < 4; ++nt)
        acc[mt][nt] = __builtin_amdgcn_mfma_f32_16x16x32_f16(af[mt], bf[nt], acc[mt][nt], 0, 0, 0);
    __syncthreads();
  }
  // epilogue: C/D layout col = lane&15, row = quad*4 + reg
#pragma unroll
  for (int nt = 0; nt < 4; ++nt) {
    const int col = n0 + nh + nt * 16 + l15;
    const float bias = biasc[col];
#pragma unroll
    for (int mt = 0; mt < 4; ++mt) {
      const int mrow = m0 + mh + mt * 16 + quad * 4;
#pragma unroll
      for (int j = 0; j < 4; ++j)
        xproj[(size_t)(mrow + j) * G4 + col] = (_Float16)(acc[mt][nt][j] + bias);
    }
  }
}

// ---------------------------------------------------------------------------
// K2: sequential LSTM. One workgroup per batch element; 512 threads.
// Thread t owns gate rows t and t+512. W_hh f16: 80 dword-pairs/row in VGPRs,
// 48 streamed from L2 each step. h broadcast from LDS (f16 pairs).
// ---------------------------------------------------------------------------
__global__ __launch_bounds__(512, 2) void lstm_seq(
    const _Float16* __restrict__ xproj, const uint32_t* __restrict__ wreg,
    const uint32_t* __restrict__ wst4, float* __restrict__ hfin) {
  __shared__ __align__(16) uint32_t hsm[128];   // 256 f16 h values
  __shared__ float gsm[G4];
  const int t0 = threadIdx.x;
  const int t1 = t0 + 512;
  const int b = blockIdx.x;

  uint32_t w0[80], w1[80];
#pragma unroll
  for (int c = 0; c < 80; ++c) { w0[c] = wreg[c * G4 + t0]; w1[c] = wreg[c * G4 + t1]; }

  if (t0 < 128) hsm[t0] = 0;
  float cst = 0.f;
  const _Float16* xp = xproj + (size_t)b * TT * G4;
  const uint4* wst = (const uint4*)wst4;
  _Float16 xn0 = xp[t0], xn1 = xp[t1];
  __syncthreads();

  for (int t = 0; t < TT; ++t) {
    float a0[4], a1[4];
    a0[0] = (float)xn0; a0[1] = 0.f; a0[2] = 0.f; a0[3] = 0.f;
    a1[0] = (float)xn1; a1[1] = 0.f; a1[2] = 0.f; a1[3] = 0.f;
    const int tn = (t < TT - 1) ? t + 1 : t;
    xn0 = xp[(size_t)tn * G4 + t0];   // prefetch next step
    xn1 = xp[(size_t)tn * G4 + t1];
    const uint4* h4 = (const uint4*)hsm;
    // register-resident part: k-pairs 0..79
#pragma unroll
    for (int cc = 0; cc < 20; ++cc) {
      uint4 hc = h4[cc];
      a0[0] = fdot2(w0[cc * 4 + 0], hc.x, a0[0]);
      a0[1] = fdot2(w0[cc * 4 + 1], hc.y, a0[1]);
      a0[2] = fdot2(w0[cc * 4 + 2], hc.z, a0[2]);
      a0[3] = fdot2(w0[cc * 4 + 3], hc.w, a0[3]);
      a1[0] = fdot2(w1[cc * 4 + 0], hc.x, a1[0]);
      a1[1] = fdot2(w1[cc * 4 + 1], hc.y, a1[1]);
      a1[2] = fdot2(w1[cc * 4 + 2], hc.z, a1[2]);
      a1[3] = fdot2(w1[cc * 4 + 3], hc.w, a1[3]);
    }
    // streamed part: k-pairs 80..127 (L2-resident, same for all WGs)
#pragma unroll
    for (int c = 0; c < 12; ++c) {
      uint4 wa = wst[c * G4 + t0];
      uint4 wb = wst[c * G4 + t1];
      uint4 hc = h4[20 + c];
      a0[0] = fdot2(wa.x, hc.x, a0[0]);
      a0[1] = fdot2(wa.y, hc.y, a0[1]);
      a0[2] = fdot2(wa.z, hc.z, a0[2]);
      a0[3] = fdot2(wa.w, hc.w, a0[3]);
      a1[0] = fdot2(wb.x, hc.x, a1[0]);
      a1[1] = fdot2(wb.y, hc.y, a1[1]);
      a1[2] = fdot2(wb.z, hc.z, a1[2]);
      a1[3] = fdot2(wb.w, hc.w, a1[3]);
    }
    gsm[t0] = (a0[0] + a0[1]) + (a0[2] + a0[3]);
    gsm[t1] = (a1[0] + a1[1]) + (a1[2] + a1[3]);
    __syncthreads();
    if (t0 < HH) {
      float ig = sigmf(gsm[t0]);
      float fg = sigmf(gsm[HH + t0]);
      float gg = tanhf2(gsm[2 * HH + t0]);
      float og = sigmf(gsm[3 * HH + t0]);
      cst = fg * cst + ig * gg;
      float h = og * tanhf2(cst);
      ((_Float16*)hsm)[t0] = (_Float16)h;
      if (t == TT - 1) hfin[(size_t)b * HH + t0] = h;
    }
    __syncthreads();
  }
}

// ---------------------------------------------------------------------------
// K3: out[b][c] = h_last[b] . W_cls[c] + b_cls[c]
// ---------------------------------------------------------------------------
__global__ __launch_bounds__(256) void cls_k(
    const float* __restrict__ hfin, const float* __restrict__ Wcls,
    const float* __restrict__ bcls, float* __restrict__ out) {
  __shared__ float part[4][NC];
  const int b = blockIdx.x, tid = threadIdx.x;
  const int lane = tid & 63, wave = tid >> 6;
  float hv = hfin[(size_t)b * HH + tid];
#pragma unroll
  for (int c = 0; c < NC; ++c) {
    float p = hv * Wcls[c * HH + tid];
#pragma unroll
    for (int off = 32; off >= 1; off >>= 1) p += __shfl_down(p, off, 64);
    if (lane == 0) part[wave][c] = p;
  }
  __syncthreads();
  if (tid < NC) {
    out[(size_t)b * NC + tid] =
        part[0][tid] + part[1][tid] + part[2][tid] + part[3][tid] + bcls[tid];
  }
}

// ---------------------------------------------------------------------------
extern "C" void kernel_launch(void* const* d_in, const int* in_sizes, int n_in,
                              void* d_out, int out_size, void* d_ws, size_t ws_size,
                              hipStream_t stream) {
  (void)in_sizes; (void)n_in; (void)out_size; (void)ws_size;
  const float* x    = (const float*)d_in[0];
  const float* key  = (const float*)d_in[1];
  const float* Wih  = (const float*)d_in[2];
  const float* Whh  = (const float*)d_in[3];
  const float* bih  = (const float*)d_in[4];
  const float* bhh  = (const float*)d_in[5];
  const float* Wcls = (const float*)d_in[6];
  const float* bcls = (const float*)d_in[7];
  float* out = (float*)d_out;

  char* ws = (char*)d_ws;
  size_t off = 0;
  _Float16* xproj = (_Float16*)(ws + off); off += (size_t)BB * TT * G4 * 2;  // 256 MiB
  uint32_t* wreg  = (uint32_t*)(ws + off); off += (size_t)80 * G4 * 4;
  uint32_t* wst   = (uint32_t*)(ws + off); off += (size_t)12 * G4 * 16;
  _Float16* WcT   = (_Float16*)(ws + off); off += (size_t)G4 * II * 2;
  float* biasc    = (float*)(ws + off);    off += (size_t)G4 * 4;
  float* hfin     = (float*)(ws + off);    off += (size_t)BB * HH * 4;

  hipLaunchKernelGGL(prep_wc,  dim3(II),  dim3(G4),  0, stream, key, Wih, bih, bhh, WcT, biasc);
  hipLaunchKernelGGL(prep_whh, dim3(512), dim3(256), 0, stream, Whh, wreg, wst);
  hipLaunchKernelGGL(gemm_xproj, dim3(G4 / 128, (BB * TT) / 128), dim3(256), 0, stream,
                     x, WcT, biasc, xproj);
  hipLaunchKernelGGL(lstm_seq, dim3(BB), dim3(512), 0, stream, xproj, wreg, wst, hfin);
  hipLaunchKernelGGL(cls_k,    dim3(BB), dim3(256), 0, stream, hfin, Wcls, bcls, out);
}

// Round 2
// 6874.552 us; speedup vs baseline: 1.0247x; 1.0247x over previous
//
#include <hip/hip_runtime.h>
#include <hip/hip_bf16.h>
#include <stdint.h>

#define BB   64
#define TT   2048
#define II   256
#define HH   256
#define G4   1024   // 4*H
#define NC   10

typedef _Float16 half2v __attribute__((ext_vector_type(2)));
typedef _Float16 half8v __attribute__((ext_vector_type(8)));
typedef float    float4v __attribute__((ext_vector_type(4)));

__device__ __forceinline__ float fdot2(uint32_t w, uint32_t h, float acc) {
  return __builtin_amdgcn_fdot2(__builtin_bit_cast(half2v, w),
                                __builtin_bit_cast(half2v, h), acc, false);
}
__device__ __forceinline__ float sigmf(float v) { return 1.f / (1.f + __expf(-v)); }
__device__ __forceinline__ float tanhf2(float v) { float e = __expf(2.f * v); return 1.f - 2.f / (e + 1.f); }

// Barrier WITHOUT vmcnt drain: only LDS ops need ordering across the barrier.
// Keeps the global xproj prefetch in flight (plain __syncthreads emits
// s_waitcnt vmcnt(0) which would stall on it every step).
__device__ __forceinline__ void bar_lds() {
  asm volatile("s_waitcnt lgkmcnt(0)\n\ts_barrier" ::: "memory");
}

// ---------------------------------------------------------------------------
// K0a: WcT[g][i] = sum_j key[i][j] * W_ih[g][j]  (f16), biasc[g] = b_ih+b_hh
// ---------------------------------------------------------------------------
__global__ __launch_bounds__(1024) void prep_wc(
    const float* __restrict__ key, const float* __restrict__ Wih,
    const float* __restrict__ bih, const float* __restrict__ bhh,
    _Float16* __restrict__ WcT, float* __restrict__ biasc) {
  __shared__ float krow[II];
  const int i = blockIdx.x;
  const int g = threadIdx.x;
  if (g < II) krow[g] = key[(size_t)i * II + g];
  __syncthreads();
  const float4* w4 = (const float4*)(Wih + (size_t)g * II);
  float acc = 0.f;
#pragma unroll 8
  for (int j = 0; j < II / 4; ++j) {
    float4 w = w4[j];
    acc += w.x * krow[4 * j] + w.y * krow[4 * j + 1] + w.z * krow[4 * j + 2] + w.w * krow[4 * j + 3];
  }
  WcT[(size_t)g * II + i] = (_Float16)acc;
  if (i == 0) biasc[g] = bih[g] + bhh[g];
}

// ---------------------------------------------------------------------------
// K0c: pack W_hh rows into f16-pair dwords: wreg[kp][g], kp = 0..127
// ---------------------------------------------------------------------------
__global__ __launch_bounds__(256) void prep_whh(
    const float* __restrict__ Whh, uint32_t* __restrict__ wreg) {
  const int id = blockIdx.x * 256 + threadIdx.x;   // 131072
  const int g  = id & (G4 - 1);
  const int kp = id >> 10;                          // 0..127
  float a = Whh[(size_t)g * HH + 2 * kp];
  float b = Whh[(size_t)g * HH + 2 * kp + 1];
  half2v h = {(_Float16)a, (_Float16)b};
  wreg[kp * G4 + g] = __builtin_bit_cast(uint32_t, h);
}

// ---------------------------------------------------------------------------
// K1: xpk packed projection. Logical x_proj[m][g]; stored as [m][512] dwords:
//   dword d of row m = (x_proj[m][d] , x_proj[m][d+512]) as f16 pair.
//   128x128 tile, 256 threads, 16x16x32 f16 MFMA, fp32 acc, bias fused.
// ---------------------------------------------------------------------------
__global__ __launch_bounds__(256) void gemm_xproj(
    const float* __restrict__ x, const _Float16* __restrict__ WcT,
    const float* __restrict__ biasc, _Float16* __restrict__ xpk) {
  __shared__ __align__(16) _Float16 Asm[128][40];
  __shared__ __align__(16) _Float16 Bsm[128][40];
  const int t = threadIdx.x;
  const int n0 = blockIdx.x * 128;
  const int m0 = blockIdx.y * 128;
  const int r = t >> 1;
  const int hoff = (t & 1) * 16;
  const int lane = t & 63, wave = t >> 6;
  const int quad = lane >> 4, l15 = lane & 15;
  const int mh = (wave & 1) * 64, nh = (wave >> 1) * 64;
  float4v zero = {0.f, 0.f, 0.f, 0.f};
  float4v acc[4][4];
#pragma unroll
  for (int a = 0; a < 4; ++a)
#pragma unroll
    for (int b = 0; b < 4; ++b) acc[a][b] = zero;

  for (int kt = 0; kt < 8; ++kt) {
    const int k0 = kt * 32;
    const float4* xa = (const float4*)(x + (size_t)(m0 + r) * II + k0 + hoff);
    float4 f0 = xa[0], f1 = xa[1], f2 = xa[2], f3 = xa[3];
    half8v lo = {(_Float16)f0.x, (_Float16)f0.y, (_Float16)f0.z, (_Float16)f0.w,
                 (_Float16)f1.x, (_Float16)f1.y, (_Float16)f1.z, (_Float16)f1.w};
    half8v hi = {(_Float16)f2.x, (_Float16)f2.y, (_Float16)f2.z, (_Float16)f2.w,
                 (_Float16)f3.x, (_Float16)f3.y, (_Float16)f3.z, (_Float16)f3.w};
    const half8v* bsrc = (const half8v*)(WcT + (size_t)(n0 + r) * II + k0 + hoff);
    half8v b0 = bsrc[0], b1 = bsrc[1];
    *(half8v*)&Asm[r][hoff]     = lo;
    *(half8v*)&Asm[r][hoff + 8] = hi;
    *(half8v*)&Bsm[r][hoff]     = b0;
    *(half8v*)&Bsm[r][hoff + 8] = b1;
    __syncthreads();
    half8v af[4], bf[4];
#pragma unroll
    for (int mt = 0; mt < 4; ++mt) af[mt] = *(const half8v*)&Asm[mh + mt * 16 + l15][quad * 8];
#pragma unroll
    for (int nt = 0; nt < 4; ++nt) bf[nt] = *(const half8v*)&Bsm[nh + nt * 16 + l15][quad * 8];
#pragma unroll
    for (int mt = 0; mt < 4; ++mt)
#pragma unroll
      for (int nt = 0; nt < 4; ++nt)
        acc[mt][nt] = __builtin_amdgcn_mfma_f32_16x16x32_f16(af[mt], bf[nt], acc[mt][nt], 0, 0, 0);
    __syncthreads();
  }
  // epilogue: C/D layout col = lane&15, row = quad*4 + reg; write packed layout
  _Float16* dst = xpk;
#pragma unroll
  for (int nt = 0; nt < 4; ++nt) {
    const int col = n0 + nh + nt * 16 + l15;
    const float bias = biasc[col];
    const int cslot = (col & 511) * 2 + (col >> 9);
#pragma unroll
    for (int mt = 0; mt < 4; ++mt) {
      const int mrow = m0 + mh + mt * 16 + quad * 4;
#pragma unroll
      for (int j = 0; j < 4; ++j)
        dst[(size_t)(mrow + j) * 1024 + cslot] = (_Float16)(acc[mt][nt][j] + bias);
    }
  }
}

// ---------------------------------------------------------------------------
// K2: sequential LSTM. One WG per batch element; 512 threads, 2 gate rows
// each (t0, t0+512). ALL of W_hh register-resident (256 f16-pair dwords per
// thread -> VGPR+AGPR unified file, 2 waves/SIMD). Per step the only memory
// ops are: 1 coalesced global dword (packed xproj, prefetched 1 step ahead),
// broadcast LDS reads of h, and the small gsm/hsm handoffs.
// ---------------------------------------------------------------------------
__global__ __launch_bounds__(512, 2) void lstm_seq(
    const uint32_t* __restrict__ xpk, const uint32_t* __restrict__ wreg,
    float* __restrict__ hfin) {
  __shared__ __align__(16) uint32_t hsm[128];   // 256 f16 h values
  __shared__ float gsm[512];                    // f and o pre-activations
  const int t0 = threadIdx.x;
  const int t1 = t0 + 512;
  const int b = blockIdx.x;

  uint32_t w0[128], w1[128];
#pragma unroll
  for (int c = 0; c < 128; ++c) { w0[c] = wreg[c * G4 + t0]; w1[c] = wreg[c * G4 + t1]; }

  if (t0 < 128) hsm[t0] = 0;
  float cst = 0.f;
  const uint32_t* xp = xpk + (size_t)b * TT * 512;
  uint32_t xn = xp[t0];
  __syncthreads();

  for (int t = 0; t < TT; ++t) {
    const uint32_t xw = xn;
    const int tn = (t < TT - 1) ? t + 1 : t;
    xn = xp[(size_t)tn * 512 + t0];   // prefetch next step (stays in flight
                                      // across bar_lds: no vmcnt drain)
    half2v xh = __builtin_bit_cast(half2v, xw);
    float a0[4], a1[4];
    a0[0] = (float)xh.x; a0[1] = 0.f; a0[2] = 0.f; a0[3] = 0.f;
    a1[0] = (float)xh.y; a1[1] = 0.f; a1[2] = 0.f; a1[3] = 0.f;
    const uint4* h4 = (const uint4*)hsm;
#pragma unroll
    for (int cc = 0; cc < 32; ++cc) {
      uint4 hc = h4[cc];
      a0[0] = fdot2(w0[cc * 4 + 0], hc.x, a0[0]);
      a0[1] = fdot2(w0[cc * 4 + 1], hc.y, a0[1]);
      a0[2] = fdot2(w0[cc * 4 + 2], hc.z, a0[2]);
      a0[3] = fdot2(w0[cc * 4 + 3], hc.w, a0[3]);
      a1[0] = fdot2(w1[cc * 4 + 0], hc.x, a1[0]);
      a1[1] = fdot2(w1[cc * 4 + 1], hc.y, a1[1]);
      a1[2] = fdot2(w1[cc * 4 + 2], hc.z, a1[2]);
      a1[3] = fdot2(w1[cc * 4 + 3], hc.w, a1[3]);
    }
    const float s0 = (a0[0] + a0[1]) + (a0[2] + a0[3]);
    const float s1 = (a1[0] + a1[1]) + (a1[2] + a1[3]);
    // threads >=256 own f (row t0) and o (row t0+512) for h-index t0-256
    if (t0 >= 256) { gsm[t0 - 256] = s0; gsm[t0] = s1; }
    bar_lds();
    if (t0 < 256) {
      float ig = sigmf(s0);        // own row t0      = i gate
      float gg = tanhf2(s1);       // own row t0+512  = g gate
      float fg = sigmf(gsm[t0]);
      float og = sigmf(gsm[t0 + 256]);
      cst = fg * cst + ig * gg;
      float h = og * tanhf2(cst);
      ((_Float16*)hsm)[t0] = (_Float16)h;
      if (t == TT - 1) hfin[(size_t)b * HH + t0] = h;
    }
    bar_lds();
  }
}

// ---------------------------------------------------------------------------
// K3: out[b][c] = h_last[b] . W_cls[c] + b_cls[c]
// ---------------------------------------------------------------------------
__global__ __launch_bounds__(256) void cls_k(
    const float* __restrict__ hfin, const float* __restrict__ Wcls,
    const float* __restrict__ bcls, float* __restrict__ out) {
  __shared__ float part[4][NC];
  const int b = blockIdx.x, tid = threadIdx.x;
  const int lane = tid & 63, wave = tid >> 6;
  float hv = hfin[(size_t)b * HH + tid];
#pragma unroll
  for (int c = 0; c < NC; ++c) {
    float p = hv * Wcls[c * HH + tid];
#pragma unroll
    for (int off = 32; off >= 1; off >>= 1) p += __shfl_down(p, off, 64);
    if (lane == 0) part[wave][c] = p;
  }
  __syncthreads();
  if (tid < NC) {
    out[(size_t)b * NC + tid] =
        part[0][tid] + part[1][tid] + part[2][tid] + part[3][tid] + bcls[tid];
  }
}

// ---------------------------------------------------------------------------
extern "C" void kernel_launch(void* const* d_in, const int* in_sizes, int n_in,
                              void* d_out, int out_size, void* d_ws, size_t ws_size,
                              hipStream_t stream) {
  (void)in_sizes; (void)n_in; (void)out_size; (void)ws_size;
  const float* x    = (const float*)d_in[0];
  const float* key  = (const float*)d_in[1];
  const float* Wih  = (const float*)d_in[2];
  const float* Whh  = (const float*)d_in[3];
  const float* bih  = (const float*)d_in[4];
  const float* bhh  = (const float*)d_in[5];
  const float* Wcls = (const float*)d_in[6];
  const float* bcls = (const float*)d_in[7];
  float* out = (float*)d_out;

  char* ws = (char*)d_ws;
  size_t off = 0;
  uint32_t* xpk  = (uint32_t*)(ws + off); off += (size_t)BB * TT * 512 * 4;  // 268 MB
  uint32_t* wreg = (uint32_t*)(ws + off); off += (size_t)128 * G4 * 4;
  _Float16* WcT  = (_Float16*)(ws + off); off += (size_t)G4 * II * 2;
  float* biasc   = (float*)(ws + off);    off += (size_t)G4 * 4;
  float* hfin    = (float*)(ws + off);    off += (size_t)BB * HH * 4;

  hipLaunchKernelGGL(prep_wc,  dim3(II),  dim3(G4),  0, stream, key, Wih, bih, bhh, WcT, biasc);
  hipLaunchKernelGGL(prep_whh, dim3(512), dim3(256), 0, stream, Whh, wreg);
  hipLaunchKernelGGL(gemm_xproj, dim3(G4 / 128, (BB * TT) / 128), dim3(256), 0, stream,
                     x, WcT, biasc, (_Float16*)xpk);
  hipLaunchKernelGGL(lstm_seq, dim3(BB), dim3(512), 0, stream, xpk, wreg, hfin);
  hipLaunchKernelGGL(cls_k,    dim3(BB), dim3(256), 0, stream, hfin, Wcls, bcls, out);
}

// Round 3
// 4485.696 us; speedup vs baseline: 1.5705x; 1.5325x over previous
//
#include <hip/hip_runtime.h>
#include <hip/hip_bf16.h>
#include <stdint.h>

#define BB   64
#define TT   2048
#define II   256
#define HH   256
#define G4   1024   // 4*H
#define NC   10

typedef _Float16 half2v __attribute__((ext_vector_type(2)));
typedef _Float16 half8v __attribute__((ext_vector_type(8)));
typedef float    float4v __attribute__((ext_vector_type(4)));

__device__ __forceinline__ float fdot2(uint32_t w, uint32_t h, float acc) {
  return __builtin_amdgcn_fdot2(__builtin_bit_cast(half2v, w),
                                __builtin_bit_cast(half2v, h), acc, false);
}
__device__ __forceinline__ float sigmf(float v) { return 1.f / (1.f + __expf(-v)); }
__device__ __forceinline__ float tanhf2(float v) { float e = __expf(2.f * v); return 1.f - 2.f / (e + 1.f); }

// Barrier WITHOUT vmcnt drain: keeps the global xpk prefetch in flight.
__device__ __forceinline__ void bar_lds() {
  asm volatile("s_waitcnt lgkmcnt(0)\n\ts_barrier" ::: "memory");
}

// ---------------------------------------------------------------------------
// K0a: WcT[g][i] = sum_j key[i][j] * W_ih[g][j]  (f16), biasc[g] = b_ih+b_hh
// ---------------------------------------------------------------------------
__global__ __launch_bounds__(1024) void prep_wc(
    const float* __restrict__ key, const float* __restrict__ Wih,
    const float* __restrict__ bih, const float* __restrict__ bhh,
    _Float16* __restrict__ WcT, float* __restrict__ biasc) {
  __shared__ float krow[II];
  const int i = blockIdx.x;
  const int g = threadIdx.x;
  if (g < II) krow[g] = key[(size_t)i * II + g];
  __syncthreads();
  const float4* w4 = (const float4*)(Wih + (size_t)g * II);
  float acc = 0.f;
#pragma unroll 8
  for (int j = 0; j < II / 4; ++j) {
    float4 w = w4[j];
    acc += w.x * krow[4 * j] + w.y * krow[4 * j + 1] + w.z * krow[4 * j + 2] + w.w * krow[4 * j + 3];
  }
  WcT[(size_t)g * II + i] = (_Float16)acc;
  if (i == 0) biasc[g] = bih[g] + bhh[g];
}

// ---------------------------------------------------------------------------
// K0c: pack W_hh f16-pair dwords.
//   kp 0..111  -> wrg[kp][g]                (register-resident in lstm_seq)
//   kp 112..127-> wld[(c*512+t)*4+j] 16B blk (LDS-resident in lstm_seq)
//     where t = g&511, c = (g>>9)*4 + (kp-112)/4, j = (kp-112)&3
// ---------------------------------------------------------------------------
__global__ __launch_bounds__(256) void prep_whh(
    const float* __restrict__ Whh, uint32_t* __restrict__ wrg, uint32_t* __restrict__ wld) {
  const int id = blockIdx.x * 256 + threadIdx.x;   // 131072 = 1024 rows * 128 kp
  const int g  = id & (G4 - 1);
  const int kp = id >> 10;                          // 0..127
  float a = Whh[(size_t)g * HH + 2 * kp];
  float b = Whh[(size_t)g * HH + 2 * kp + 1];
  half2v h = {(_Float16)a, (_Float16)b};
  uint32_t packed = __builtin_bit_cast(uint32_t, h);
  if (kp < 112) {
    wrg[kp * G4 + g] = packed;
  } else {
    const int t = g & 511, hh = g >> 9;
    const int d = kp - 112;                         // 0..15
    const int c = hh * 4 + (d >> 2), j = d & 3;
    wld[(size_t)(c * 512 + t) * 4 + j] = packed;
  }
}

// ---------------------------------------------------------------------------
// K1: packed x-projection GEMM (unchanged). Logical x_proj[m][g]; stored as
//   [m][512] dwords: dword d = (x_proj[m][d], x_proj[m][d+512]) as f16 pair.
// ---------------------------------------------------------------------------
__global__ __launch_bounds__(256) void gemm_xproj(
    const float* __restrict__ x, const _Float16* __restrict__ WcT,
    const float* __restrict__ biasc, _Float16* __restrict__ xpk) {
  __shared__ __align__(16) _Float16 Asm[128][40];
  __shared__ __align__(16) _Float16 Bsm[128][40];
  const int t = threadIdx.x;
  const int n0 = blockIdx.x * 128;
  const int m0 = blockIdx.y * 128;
  const int r = t >> 1;
  const int hoff = (t & 1) * 16;
  const int lane = t & 63, wave = t >> 6;
  const int quad = lane >> 4, l15 = lane & 15;
  const int mh = (wave & 1) * 64, nh = (wave >> 1) * 64;
  float4v zero = {0.f, 0.f, 0.f, 0.f};
  float4v acc[4][4];
#pragma unroll
  for (int a = 0; a < 4; ++a)
#pragma unroll
    for (int b = 0; b < 4; ++b) acc[a][b] = zero;

  for (int kt = 0; kt < 8; ++kt) {
    const int k0 = kt * 32;
    const float4* xa = (const float4*)(x + (size_t)(m0 + r) * II + k0 + hoff);
    float4 f0 = xa[0], f1 = xa[1], f2 = xa[2], f3 = xa[3];
    half8v lo = {(_Float16)f0.x, (_Float16)f0.y, (_Float16)f0.z, (_Float16)f0.w,
                 (_Float16)f1.x, (_Float16)f1.y, (_Float16)f1.z, (_Float16)f1.w};
    half8v hi = {(_Float16)f2.x, (_Float16)f2.y, (_Float16)f2.z, (_Float16)f2.w,
                 (_Float16)f3.x, (_Float16)f3.y, (_Float16)f3.z, (_Float16)f3.w};
    const half8v* bsrc = (const half8v*)(WcT + (size_t)(n0 + r) * II + k0 + hoff);
    half8v b0 = bsrc[0], b1 = bsrc[1];
    *(half8v*)&Asm[r][hoff]     = lo;
    *(half8v*)&Asm[r][hoff + 8] = hi;
    *(half8v*)&Bsm[r][hoff]     = b0;
    *(half8v*)&Bsm[r][hoff + 8] = b1;
    __syncthreads();
    half8v af[4], bf[4];
#pragma unroll
    for (int mt = 0; mt < 4; ++mt) af[mt] = *(const half8v*)&Asm[mh + mt * 16 + l15][quad * 8];
#pragma unroll
    for (int nt = 0; nt < 4; ++nt) bf[nt] = *(const half8v*)&Bsm[nh + nt * 16 + l15][quad * 8];
#pragma unroll
    for (int mt = 0; mt < 4; ++mt)
#pragma unroll
      for (int nt = 0; nt < 4; ++nt)
        acc[mt][nt] = __builtin_amdgcn_mfma_f32_16x16x32_f16(af[mt], bf[nt], acc[mt][nt], 0, 0, 0);
    __syncthreads();
  }
  _Float16* dst = xpk;
#pragma unroll
  for (int nt = 0; nt < 4; ++nt) {
    const int col = n0 + nh + nt * 16 + l15;
    const float bias = biasc[col];
    const int cslot = (col & 511) * 2 + (col >> 9);
#pragma unroll
    for (int mt = 0; mt < 4; ++mt) {
      const int mrow = m0 + mh + mt * 16 + quad * 4;
#pragma unroll
      for (int j = 0; j < 4; ++j)
        dst[(size_t)(mrow + j) * 1024 + cslot] = (_Float16)(acc[mt][nt][j] + bias);
    }
  }
}

// ---------------------------------------------------------------------------
// K2: sequential LSTM. One WG / batch element; 512 threads; rows t0, t0+512.
// Weight split sized to the unified 256-reg/thread cap (2 waves/SIMD):
//   kpairs 0..111 of both rows -> 224 register dwords (fits with ~25 working)
//   kpairs 112..127            -> 64 KB LDS, ds_read_b128 per step
// Per step: 1 coalesced global dword (xpk prefetch, never drained by the
// custom barrier), uniform h broadcasts, 8 LDS weight reads. No L2 restream.
// ---------------------------------------------------------------------------
__global__ __launch_bounds__(512, 2) void lstm_seq(
    const uint32_t* __restrict__ xpk, const uint32_t* __restrict__ wrg,
    const uint4* __restrict__ wld, float* __restrict__ hfin) {
  __shared__ __align__(16) uint4 wsm[8 * 512];     // 64 KB weight tail
  __shared__ __align__(16) uint32_t hsm[128];      // 256 f16 h
  __shared__ float gsm[512];                       // f,o pre-activations
  const int t0 = threadIdx.x, t1 = t0 + 512, b = blockIdx.x;

  uint32_t w0[112], w1[112];
#pragma unroll
  for (int c = 0; c < 112; ++c) { w0[c] = wrg[c * G4 + t0]; w1[c] = wrg[c * G4 + t1]; }
#pragma unroll
  for (int c = 0; c < 8; ++c) wsm[c * 512 + t0] = wld[c * 512 + t0];
  if (t0 < 128) hsm[t0] = 0;
  float cst = 0.f, hlast = 0.f;
  const uint32_t* xp = xpk + (size_t)b * TT * 512 + t0;
  uint32_t xn = xp[0];
  __syncthreads();

  for (int t = 0; t < TT; ++t) {
    const uint32_t xw = xn;
    xn = xp[(size_t)((t < TT - 1) ? t + 1 : t) * 512];   // prefetch next step
    float a00 = 0.f, a01 = 0.f, a10 = 0.f, a11 = 0.f;
    const uint4* h4 = (const uint4*)hsm;
#pragma unroll
    for (int cc = 0; cc < 28; ++cc) {          // register-resident kpairs
      uint4 hc = h4[cc];
      a00 = fdot2(w0[4 * cc + 0], hc.x, a00);
      a01 = fdot2(w0[4 * cc + 1], hc.y, a01);
      a00 = fdot2(w0[4 * cc + 2], hc.z, a00);
      a01 = fdot2(w0[4 * cc + 3], hc.w, a01);
      a10 = fdot2(w1[4 * cc + 0], hc.x, a10);
      a11 = fdot2(w1[4 * cc + 1], hc.y, a11);
      a10 = fdot2(w1[4 * cc + 2], hc.z, a10);
      a11 = fdot2(w1[4 * cc + 3], hc.w, a11);
    }
#pragma unroll
    for (int j = 0; j < 4; ++j) {              // LDS-resident tail kpairs
      uint4 hc = h4[28 + j];
      uint4 wa = wsm[j * 512 + t0];
      uint4 wb = wsm[(4 + j) * 512 + t0];
      a00 = fdot2(wa.x, hc.x, a00);
      a01 = fdot2(wa.y, hc.y, a01);
      a00 = fdot2(wa.z, hc.z, a00);
      a01 = fdot2(wa.w, hc.w, a01);
      a10 = fdot2(wb.x, hc.x, a10);
      a11 = fdot2(wb.y, hc.y, a11);
      a10 = fdot2(wb.z, hc.z, a10);
      a11 = fdot2(wb.w, hc.w, a11);
    }
    half2v xh = __builtin_bit_cast(half2v, xw);
    const float s0 = (a00 + a01) + (float)xh.x;
    const float s1 = (a10 + a11) + (float)xh.y;
    if (t0 >= 256) { gsm[t0 - 256] = s0; gsm[t0] = s1; }
    bar_lds();
    if (t0 < 256) {
      float ig = sigmf(s0);          // row t0       = i gate
      float gg = tanhf2(s1);         // row t0+512   = g gate
      float fg = sigmf(gsm[t0]);
      float og = sigmf(gsm[t0 + 256]);
      cst = fg * cst + ig * gg;
      hlast = og * tanhf2(cst);
      ((_Float16*)hsm)[t0] = (_Float16)hlast;
    }
    bar_lds();
  }
  if (t0 < 256) hfin[(size_t)b * HH + t0] = hlast;
}

// ---------------------------------------------------------------------------
// K3: out[b][c] = h_last[b] . W_cls[c] + b_cls[c]
// ---------------------------------------------------------------------------
__global__ __launch_bounds__(256) void cls_k(
    const float* __restrict__ hfin, const float* __restrict__ Wcls,
    const float* __restrict__ bcls, float* __restrict__ out) {
  __shared__ float part[4][NC];
  const int b = blockIdx.x, tid = threadIdx.x;
  const int lane = tid & 63, wave = tid >> 6;
  float hv = hfin[(size_t)b * HH + tid];
#pragma unroll
  for (int c = 0; c < NC; ++c) {
    float p = hv * Wcls[c * HH + tid];
#pragma unroll
    for (int off = 32; off >= 1; off >>= 1) p += __shfl_down(p, off, 64);
    if (lane == 0) part[wave][c] = p;
  }
  __syncthreads();
  if (tid < NC) {
    out[(size_t)b * NC + tid] =
        part[0][tid] + part[1][tid] + part[2][tid] + part[3][tid] + bcls[tid];
  }
}

// ---------------------------------------------------------------------------
extern "C" void kernel_launch(void* const* d_in, const int* in_sizes, int n_in,
                              void* d_out, int out_size, void* d_ws, size_t ws_size,
                              hipStream_t stream) {
  (void)in_sizes; (void)n_in; (void)out_size; (void)ws_size;
  const float* x    = (const float*)d_in[0];
  const float* key  = (const float*)d_in[1];
  const float* Wih  = (const float*)d_in[2];
  const float* Whh  = (const float*)d_in[3];
  const float* bih  = (const float*)d_in[4];
  const float* bhh  = (const float*)d_in[5];
  const float* Wcls = (const float*)d_in[6];
  const float* bcls = (const float*)d_in[7];
  float* out = (float*)d_out;

  char* ws = (char*)d_ws;
  size_t off = 0;
  uint32_t* xpk  = (uint32_t*)(ws + off); off += (size_t)BB * TT * 512 * 4;  // 268 MB
  uint32_t* wrg  = (uint32_t*)(ws + off); off += (size_t)112 * G4 * 4;
  uint32_t* wld  = (uint32_t*)(ws + off); off += (size_t)8 * 512 * 16;       // 64 KB
  _Float16* WcT  = (_Float16*)(ws + off); off += (size_t)G4 * II * 2;
  float* biasc   = (float*)(ws + off);    off += (size_t)G4 * 4;
  float* hfin    = (float*)(ws + off);    off += (size_t)BB * HH * 4;

  hipLaunchKernelGGL(prep_wc,  dim3(II),  dim3(G4),  0, stream, key, Wih, bih, bhh, WcT, biasc);
  hipLaunchKernelGGL(prep_whh, dim3(512), dim3(256), 0, stream, Whh, wrg, wld);
  hipLaunchKernelGGL(gemm_xproj, dim3(G4 / 128, (BB * TT) / 128), dim3(256), 0, stream,
                     x, WcT, biasc, (_Float16*)xpk);
  hipLaunchKernelGGL(lstm_seq, dim3(BB), dim3(512), 0, stream, xpk, wrg, (const uint4*)wld, hfin);
  hipLaunchKernelGGL(cls_k,    dim3(BB), dim3(256), 0, stream, hfin, Wcls, bcls, out);
}